// Round 7
// baseline (1189.309 us; speedup 1.0000x reference)
//
#include <hip/hip_runtime.h>
#include <math.h>
#include <stdint.h>

#define E_N 19
#define H_N 32
#define T_N 2048
#define B_N 64
#define G_N 128      // 4*H gate rows per chain
#define XCHUNK 64    // timesteps per x register-stage round
#define LOG2E 1.4426950408889634f

typedef _Float16 half2_t __attribute__((ext_vector_type(2)));
typedef int v2i_t __attribute__((ext_vector_type(2)));

__device__ __forceinline__ float sigm_rcp(float e) {  // 1/(1+e)
    return __builtin_amdgcn_rcpf(1.0f + e);
}

// DPP ctrl encodings (gfx9+ standard)
#define DPP_XOR1  0xB1   // quad_perm [1,0,3,2]  : lane ^ 1
#define DPP_XOR2  0x4E   // quad_perm [2,3,0,1]  : lane ^ 2
#define DPP_HMIRR 0x141  // row_half_mirror      : lane ^ 7  (within 16-row)
#define DPP_MIRR  0x140  // row_mirror           : lane ^ 15 (within 16-row)
#define MOVDPP(x, ctrl) ((uint32_t)__builtin_amdgcn_mov_dpp((int)(x), (ctrl), 0xF, 0xF, false))

// One WAVE per chain (b,e,dir), R1 lane mapping: a = lane&31, half = lane>>5.
//   half0 lane a owns rows i_a (a)    and g_a (a+64)
//   half1 lane a owns rows f_a (a+32) and o_a (a+96)
//
// ZERO LDS. The h broadcast (the old ds_write+ds_read round trip, ~200-350cy
// of per-step critical path) is replaced by a register-only DPP all-gather:
//   h_all[a] on all lanes (permlane32_swap + select, HW-verified this session)
//   pair (h[a], h[a^16]) via __shfl_xor(.,16) + cvt + shift/or pack
//   15x v_mov_dpp (xor1/xor2/half_mirror/mirror - all orientation-certain
//   involutions) -> 16 packed regs = all 32 h values, lane-permuted.
// The lane-dependent value order is folded into the WEIGHT layout at load
// time (dot products are order-invariant): reg m elem e holds h[a^XT0[m]^16e],
// so lane a loads w[a^XT0[m]] / w[a^XT0[m]^16] into packed slot m.
// Index algebra re-verified: R5=HMIRR(R1): lane a <- lane a^7 holding h[(a^7)^1]
// = h[a^6] = XT0[5]; R12=MIRR(R4): h[(a^15)^7] = h[a^8] = XT0[12]. ✓
// x is register-staged (64 steps/round) and broadcast via v_readlane (SALU).
__global__ __launch_bounds__(64)
__attribute__((amdgpu_waves_per_eu(3, 3)))
void lstm_chain_kernel(
    const float* __restrict__ x,     // [B, T, E]
    const float* __restrict__ w_ih,  // [E, 2, 4H]
    const float* __restrict__ w_hh,  // [E, 2, 4H, H]
    const float* __restrict__ b_ih,  // [E, 2, 4H]
    const float* __restrict__ b_hh,  // [E, 2, 4H]
    float* __restrict__ hT)          // [B, E, 2, H]
{
    const int lane  = threadIdx.x;
    const int chain = blockIdx.x;            // b*(E*2) + e*2 + d
    const int b  = chain / (E_N * 2);
    const int ed = chain - b * (E_N * 2);
    const int e  = ed >> 1;
    const int d  = ed & 1;
    const int a    = lane & 31;
    const int half = lane >> 5;

    const int r1 = a + 32 * half;        // i_a (half0) or f_a (half1) -> sigmoid
    const int r2 = a + 64 + 32 * half;   // g_a (half0, tanh) or o_a (half1, sigmoid)

    // value-index xor pattern of the DPP gather (elem0; elem1 = elem0^16)
    const int XT0[16] = {0,1,2,3, 7,6,5,4, 15,14,13,12, 8,9,10,11};

    // ---- load fp32 weights PRE-PERMUTED to the gather order, pack fp16 ----
    const float* wr1 = w_hh + ((size_t)ed * G_N + r1) * H_N;
    const float* wr2 = w_hh + ((size_t)ed * G_N + r2) * H_N;
    uint32_t w1p[16], w2p[16];
    #pragma unroll
    for (int m = 0; m < 16; ++m) {
        const int k0 = a ^ XT0[m];
        const int k1 = k0 ^ 16;
        half2_t p1 = { (_Float16)wr1[k0], (_Float16)wr1[k1] };
        half2_t p2 = { (_Float16)wr2[k0], (_Float16)wr2[k1] };
        w1p[m] = __builtin_bit_cast(uint32_t, p1);
        w2p[m] = __builtin_bit_cast(uint32_t, p2);
    }

    const float wih1  = w_ih[(size_t)ed * G_N + r1];
    const float wih2  = w_ih[(size_t)ed * G_N + r2];
    const float bias1 = b_ih[(size_t)ed * G_N + r1] + b_hh[(size_t)ed * G_N + r1];
    const float bias2 = b_ih[(size_t)ed * G_N + r2] + b_hh[(size_t)ed * G_N + r2];

    // act2: half0 -> tanh(g) = 2*sigm(2g)-1 ; half1 -> sigmoid(o)
    const float K2 = half ? (-LOG2E) : (-2.0f * LOG2E);
    const float A2 = half ?  1.0f :  2.0f;
    const float B2 = half ?  0.0f : -1.0f;

    float c = 0.0f;       // valid on half1
    float h = 0.0f;       // valid on half1
    float h_all = 0.0f;   // valid on ALL lanes: h[a]

    const float* xbase = x + (size_t)b * T_N * E_N + e;
    float xcur, xnext = 0.0f;
    {
        const int tp = d ? (T_N - 1 - lane) : lane;
        xcur = xbase[(size_t)tp * E_N];
    }

    for (int t0 = 0; t0 < T_N; t0 += XCHUNK) {
        // PIN: keep the 32 packed weight regs live across the inner loop (no-op).
        #pragma unroll
        for (int m = 0; m < 16; ++m) {
            asm volatile("" : "+v"(w1p[m]), "+v"(w2p[m]));
        }
        // prefetch next 64 x values into a register (HBM latency hides under 64 steps)
        if (t0 + XCHUNK < T_N) {
            const int tn = t0 + XCHUNK + lane;
            const int tp = d ? (T_N - 1 - tn) : tn;
            xnext = xbase[(size_t)tp * E_N];
        }

        #pragma unroll 1
        for (int tl = 0; tl < XCHUNK; ++tl) {
            // x broadcast: SALU readlane (no LDS, no lgkm wait)
            const float sx = __builtin_bit_cast(float,
                __builtin_amdgcn_readlane(__builtin_bit_cast(int, xcur), tl));

            // ---- register-only h all-gather ----
            const float hx16 = __shfl_xor(h_all, 16);                 // h[a^16]
            const uint32_t hb0 = (uint32_t)__builtin_bit_cast(uint16_t, (_Float16)h_all);
            const uint32_t hb1 = (uint32_t)__builtin_bit_cast(uint16_t, (_Float16)hx16);
            const uint32_t R0  = (hb1 << 16) | hb0;      // (h[a], h[a^16]) packed
            const uint32_t R1  = MOVDPP(R0, DPP_XOR1);   // (a^1,  a^17)
            const uint32_t R2  = MOVDPP(R0, DPP_XOR2);   // (a^2,  a^18)
            const uint32_t R3  = MOVDPP(R1, DPP_XOR2);   // (a^3,  a^19)
            const uint32_t R4  = MOVDPP(R0, DPP_HMIRR);  // (a^7,  a^23)
            const uint32_t R5  = MOVDPP(R1, DPP_HMIRR);  // (a^6,  a^22)
            const uint32_t R6  = MOVDPP(R2, DPP_HMIRR);  // (a^5,  a^21)
            const uint32_t R7  = MOVDPP(R3, DPP_HMIRR);  // (a^4,  a^20)
            const uint32_t R8  = MOVDPP(R0, DPP_MIRR);   // (a^15, a^31)
            const uint32_t R9  = MOVDPP(R1, DPP_MIRR);   // (a^14, a^30)
            const uint32_t R10 = MOVDPP(R2, DPP_MIRR);   // (a^13, a^29)
            const uint32_t R11 = MOVDPP(R3, DPP_MIRR);   // (a^12, a^28)
            const uint32_t R12 = MOVDPP(R4, DPP_MIRR);   // (a^8,  a^24)
            const uint32_t R13 = MOVDPP(R5, DPP_MIRR);   // (a^9,  a^25)
            const uint32_t R14 = MOVDPP(R6, DPP_MIRR);   // (a^10, a^26)
            const uint32_t R15 = MOVDPP(R7, DPP_MIRR);   // (a^11, a^27)

            // ---- gate dots: 4 x 4-deep fdot2 chains per row ----
            #define FD(Rr, wv, acc) \
                acc = __builtin_amdgcn_fdot2(__builtin_bit_cast(half2_t, Rr), \
                                             __builtin_bit_cast(half2_t, wv), acc, false)
            float s10 = fmaf(sx, wih1, bias1), s11 = 0.0f, s12 = 0.0f, s13 = 0.0f;
            float s20 = fmaf(sx, wih2, bias2), s21 = 0.0f, s22 = 0.0f, s23 = 0.0f;
            FD(R0,  w1p[0],  s10); FD(R4,  w1p[4],  s11); FD(R8,  w1p[8],  s12); FD(R12, w1p[12], s13);
            FD(R1,  w1p[1],  s10); FD(R5,  w1p[5],  s11); FD(R9,  w1p[9],  s12); FD(R13, w1p[13], s13);
            FD(R2,  w1p[2],  s10); FD(R6,  w1p[6],  s11); FD(R10, w1p[10], s12); FD(R14, w1p[14], s13);
            FD(R3,  w1p[3],  s10); FD(R7,  w1p[7],  s11); FD(R11, w1p[11], s12); FD(R15, w1p[15], s13);
            FD(R0,  w2p[0],  s20); FD(R4,  w2p[4],  s21); FD(R8,  w2p[8],  s22); FD(R12, w2p[12], s23);
            FD(R1,  w2p[1],  s20); FD(R5,  w2p[5],  s21); FD(R9,  w2p[9],  s22); FD(R13, w2p[13], s23);
            FD(R2,  w2p[2],  s20); FD(R6,  w2p[6],  s21); FD(R10, w2p[10], s22); FD(R14, w2p[14], s23);
            FD(R3,  w2p[3],  s20); FD(R7,  w2p[7],  s21); FD(R11, w2p[11], s22); FD(R15, w2p[15], s23);
            #undef FD
            const float g1 = (s10 + s11) + (s12 + s13);
            const float g2 = (s20 + s21) + (s22 + s23);

            // act1: sigmoid (i_a / f_a); act2: tanh(g_a) / sigmoid(o_a)
            const float act1 = sigm_rcp(__builtin_amdgcn_exp2f(g1 * (-LOG2E)));
            const float act2 = fmaf(A2, sigm_rcp(__builtin_amdgcn_exp2f(g2 * K2)), B2);

            const float ig  = act1 * act2;            // half0: i*g (valid)
            const int igb   = __builtin_bit_cast(int, ig);
            const v2i_t pr  = __builtin_amdgcn_permlane32_swap(igb, igb, false, false);
            const float igx = __builtin_bit_cast(float, pr.x ^ pr.y ^ igb);  // i*g on half1

            // valid on half1 (half0 computes bounded garbage on same instrs)
            c = fmaf(act1, c, igx);                                   // f*c + i*g
            const float tc = fmaf(2.0f, sigm_rcp(
                __builtin_amdgcn_exp2f(c * (-2.0f * LOG2E))), -1.0f); // tanh(c)
            h = act2 * tc;                                            // o * tanh(c)

            // h_all = valid h[a] on every lane (partner copy for half0)
            const int hb      = __builtin_bit_cast(int, h);
            const v2i_t ph    = __builtin_amdgcn_permlane32_swap(hb, hb, false, false);
            const float hpart = __builtin_bit_cast(float, ph.x ^ ph.y ^ hb);
            h_all = half ? h : hpart;
        }
        xcur = xnext;
    }

    if (half) {
        hT[((size_t)(b * E_N + e) * 2 + d) * H_N + a] = h;
    }
}

// LayerNorm over 64 feats per (b,e), mean over e, FC -> out[b]. One wave per b.
__global__ __launch_bounds__(64) void head_kernel(
    const float* __restrict__ hT,      // [B, E, 64]
    const float* __restrict__ ln_gamma,// [E, 64]
    const float* __restrict__ ln_beta, // [E, 64]
    const float* __restrict__ fc_w,    // [64]
    const float* __restrict__ fc_b,    // [1]
    float* __restrict__ out)           // [B]
{
    const int b = blockIdx.x;
    const int f = threadIdx.x; // 0..63

    float acc = 0.0f;
    for (int e = 0; e < E_N; ++e) {
        const float v = hT[(size_t)(b * E_N + e) * 64 + f];
        float s = v, s2 = v * v;
        #pragma unroll
        for (int off = 32; off > 0; off >>= 1) {
            s  += __shfl_xor(s,  off);
            s2 += __shfl_xor(s2, off);
        }
        const float mean = s * (1.0f / 64.0f);
        const float var  = s2 * (1.0f / 64.0f) - mean * mean;
        const float inv  = rsqrtf(var + 1e-5f);
        acc += (v - mean) * inv * ln_gamma[e * 64 + f] + ln_beta[e * 64 + f];
    }
    float contrib = (acc * (1.0f / (float)E_N)) * fc_w[f];
    #pragma unroll
    for (int off = 32; off > 0; off >>= 1) contrib += __shfl_xor(contrib, off);
    if (f == 0) out[b] = contrib + fc_b[0];
}

extern "C" void kernel_launch(void* const* d_in, const int* in_sizes, int n_in,
                              void* d_out, int out_size, void* d_ws, size_t ws_size,
                              hipStream_t stream) {
    const float* x        = (const float*)d_in[0];
    const float* w_ih     = (const float*)d_in[1];
    const float* w_hh     = (const float*)d_in[2];
    const float* b_ih     = (const float*)d_in[3];
    const float* b_hh     = (const float*)d_in[4];
    const float* ln_gamma = (const float*)d_in[5];
    const float* ln_beta  = (const float*)d_in[6];
    const float* fc_w     = (const float*)d_in[7];
    const float* fc_b     = (const float*)d_in[8];
    float* out = (float*)d_out;
    float* hT  = (float*)d_ws;  // B*E*2*H floats

    lstm_chain_kernel<<<B_N * E_N * 2, 64, 0, stream>>>(x, w_ih, w_hh, b_ih, b_hh, hT);
    head_kernel<<<B_N, 64, 0, stream>>>(hT, ln_gamma, ln_beta, fc_w, fc_b, out);
}